// Round 1
// 2446.047 us; speedup vs baseline: 1.0881x; 1.0881x over previous
//
#include <hip/hip_runtime.h>

#define TT    1024   // timesteps
#define BATCH 2048
#define NI    6      // input dim
#define NH    38     // hidden
#define NG    152    // 4*NH
#define NCLS  8      // classes
#define NB    8      // batches per block
#define HP    40     // padded hidden row (16B-aligned float4 rows; cols 38,39 stay 0)
#define BLK   512

__device__ __forceinline__ float fsig(float v) {
    return __fdividef(1.0f, 1.0f + __expf(-v));
}
__device__ __forceinline__ float ftanh(float v) {
    return 1.0f - __fdividef(2.0f, 1.0f + __expf(2.0f * v));
}

// Role layout (8 waves, 512 threads):
//   waves 0-2, tid   0..151 : L1 lanes. pair k=tid>>1 -> (u=k%38, bp=k/38), sub=tid&1.
//                             Each lane: 4 gate rows x 20 Whh0-cols (+3 x-cols), 4 batches.
//                             Pair-combine via shfl_xor(1); pointwise 2 batches/lane.
//   tid 152..191            : idle (wave-alignment padding)
//   waves 3-7, tid 192..495 : L2 lanes. m=tid-192, k=m>>2 -> (u=k%38, bp=k/38), sub=m&3.
//                             Cols 0..75 = [Wih1(38) | Whh1(38)] quartered (20 each, padded).
//                             Butterfly shfl_xor(1),(2); pointwise 1 batch/lane.
//   tid 496..511            : x prefetch (3 elements each = 48 = NB*NI)
//
// Skew: iteration i computes h1(i) (needs h1(i-1), x(i)) and h2(i-1) (needs
// h1(i-1), h2(i-2)) -> ONE barrier per iteration. Loop runs i = 0..TT inclusive.
// Slots: h1(i) -> h1buf[i&1]; h2(i-1) -> h2buf[(i&1)^1]; final h2(TT-1) in h2buf[1].

__global__ __launch_bounds__(BLK, 2) void lstm2_kernel(
    const float* __restrict__ x,
    const float* __restrict__ Wih0, const float* __restrict__ Whh0, const float* __restrict__ b0,
    const float* __restrict__ Wih1, const float* __restrict__ Whh1, const float* __restrict__ b1,
    const float* __restrict__ Wc,   const float* __restrict__ bc,
    float* __restrict__ out)
{
    __shared__ __align__(16) float h1buf[2][NB][HP];
    __shared__ __align__(16) float h2buf[2][NB][HP];
    __shared__ __align__(16) float xbuf[2][NB][NI];

    const int tid   = threadIdx.x;
    const int bbase = blockIdx.x * NB;

    // zero state buffers (pads at cols 38,39 must stay 0 forever)
    for (int idx = tid; idx < 2 * NB * HP; idx += BLK) {
        (&h1buf[0][0][0])[idx] = 0.0f;
        (&h2buf[0][0][0])[idx] = 0.0f;
    }
    // preload x(t=0) into slot 0
    if (tid < NB * NI) {
        const int b = tid / NI, j = tid % NI;
        xbuf[0][b][j] = x[((size_t)(bbase + b) * TT + 0) * NI + j];
        xbuf[1][b][j] = 0.0f;
    }

    const bool isL1  = (tid < 152);
    const bool inL1w = (tid < 192);
    const bool isL2  = (tid >= 192) && (tid < 496);

    int u = 0, b0i = 0, cb = 0, sub = 0;
    if (isL1) {
        const int k = tid >> 1;
        u   = k % NH;
        b0i = (k / NH) * 4;      // 4 batches per pair
        sub = tid & 1;           // column-half
        cb  = sub * 20;
    } else if (isL2) {
        const int m = tid - 192;
        const int k = m >> 2;
        u   = k % NH;
        b0i = (k / NH) * 4;      // 4 batches per quad
        sub = m & 3;             // column-quarter: 0,1 -> Wih1 halves; 2,3 -> Whh1 halves
        cb  = (sub & 1) * 20;
    }

    // register-resident weights: 4 gate rows x 20 cols (+ x-cols for L1)
    float w[4][20];
    float wx[4][3];
    float bias4[4];
    #pragma unroll
    for (int g = 0; g < 4; ++g) {
        bias4[g] = 0.0f;
        wx[g][0] = wx[g][1] = wx[g][2] = 0.0f;
        #pragma unroll
        for (int kk = 0; kk < 20; ++kk) w[g][kk] = 0.0f;
    }

    if (isL1) {
        #pragma unroll
        for (int g = 0; g < 4; ++g) {
            const float* row = Whh0 + (size_t)(u + g * NH) * NH;
            #pragma unroll
            for (int kk = 0; kk < 20; ++kk)
                if (cb + kk < NH) w[g][kk] = row[cb + kk];
            const float* xrow = Wih0 + (size_t)(u + g * NH) * NI;
            #pragma unroll
            for (int j = 0; j < 3; ++j) wx[g][j] = xrow[sub * 3 + j];
            bias4[g] = b0[u + g * NH];
        }
    } else if (isL2) {
        const float* Wm = (sub < 2) ? Wih1 : Whh1;
        #pragma unroll
        for (int g = 0; g < 4; ++g) {
            const float* row = Wm + (size_t)(u + g * NH) * NH;
            #pragma unroll
            for (int kk = 0; kk < 20; ++kk)
                if (cb + kk < NH) w[g][kk] = row[cb + kk];
            bias4[g] = b1[u + g * NH];
        }
    }

    // prefetch-lane precompute: element e -> xbuf flat offset e, global base
    size_t xg0 = 0, xg1 = 0, xg2 = 0;
    int    xo0 = 0, xo1 = 0, xo2 = 0;
    if (tid >= 496) {
        const int s  = tid - 496;
        const int e0 = s, e1 = s + 16, e2 = s + 32;
        xo0 = e0; xo1 = e1; xo2 = e2;
        xg0 = (size_t)(bbase + e0 / NI) * TT * NI + (e0 % NI);
        xg1 = (size_t)(bbase + e1 / NI) * TT * NI + (e1 % NI);
        xg2 = (size_t)(bbase + e2 / NI) * TT * NI + (e2 % NI);
    }

    float cst[2] = {0.0f, 0.0f};   // L1: c for 2 batches; L2: c for 1 batch (cst[0])

    __syncthreads();

    #pragma unroll 1
    for (int i = 0; i <= TT; ++i) {
        const int cur = i & 1, prv = cur ^ 1;

        if (inL1w) {
            // ---- layer 1: h1(i) = pw(b0 + Wih0 x(i) + Whh0 h1(i-1)) ----
            if (isL1 && i < TT) {
                float acc[4][4];
                #pragma unroll
                for (int bb = 0; bb < 4; ++bb) {
                    const float* hr = &h1buf[prv][b0i + bb][cb];
                    float4 hv[5];
                    #pragma unroll
                    for (int c4 = 0; c4 < 5; ++c4) hv[c4] = *(const float4*)(hr + 4 * c4);
                    const float xv0 = xbuf[cur][b0i + bb][3 * sub + 0];
                    const float xv1 = xbuf[cur][b0i + bb][3 * sub + 1];
                    const float xv2 = xbuf[cur][b0i + bb][3 * sub + 2];
                    #pragma unroll
                    for (int g = 0; g < 4; ++g) {
                        float a = wx[g][0] * xv0 + wx[g][1] * xv1 + wx[g][2] * xv2;
                        #pragma unroll
                        for (int c4 = 0; c4 < 5; ++c4) {
                            a += w[g][4 * c4 + 0] * hv[c4].x;
                            a += w[g][4 * c4 + 1] * hv[c4].y;
                            a += w[g][4 * c4 + 2] * hv[c4].z;
                            a += w[g][4 * c4 + 3] * hv[c4].w;
                        }
                        acc[bb][g] = a;
                    }
                }
                // pair-combine: both lanes get full sums
                #pragma unroll
                for (int bb = 0; bb < 4; ++bb)
                    #pragma unroll
                    for (int g = 0; g < 4; ++g)
                        acc[bb][g] += __shfl_xor(acc[bb][g], 1);
                // pointwise: lane sub handles batches b0i + 2*sub + {0,1}
                #pragma unroll
                for (int j = 0; j < 2; ++j) {
                    float gv[4];
                    #pragma unroll
                    for (int g = 0; g < 4; ++g)
                        gv[g] = bias4[g] + (sub ? acc[2 + j][g] : acc[j][g]);
                    const float ig = fsig(gv[0]);
                    const float fg = fsig(gv[1]);
                    const float gg = ftanh(gv[2]);
                    const float og = fsig(gv[3]);
                    const float c  = fg * cst[j] + ig * gg;
                    cst[j] = c;
                    h1buf[cur][b0i + 2 * sub + j][u] = og * ftanh(c);
                }
            }
        } else if (isL2) {
            // ---- layer 2 (skewed): h2(i-1) = pw(b1 + Wih1 h1(i-1) + Whh1 h2(i-2)) ----
            if (i >= 1) {
                const float* hsrc = (sub < 2) ? &h1buf[prv][0][0] : &h2buf[cur][0][0];
                float acc[4][4];
                #pragma unroll
                for (int bb = 0; bb < 4; ++bb) {
                    const float* hr = hsrc + (b0i + bb) * HP + cb;
                    float4 hv[5];
                    #pragma unroll
                    for (int c4 = 0; c4 < 5; ++c4) hv[c4] = *(const float4*)(hr + 4 * c4);
                    #pragma unroll
                    for (int g = 0; g < 4; ++g) {
                        float a = 0.0f;
                        #pragma unroll
                        for (int c4 = 0; c4 < 5; ++c4) {
                            a += w[g][4 * c4 + 0] * hv[c4].x;
                            a += w[g][4 * c4 + 1] * hv[c4].y;
                            a += w[g][4 * c4 + 2] * hv[c4].z;
                            a += w[g][4 * c4 + 3] * hv[c4].w;
                        }
                        acc[bb][g] = a;
                    }
                }
                // butterfly over the 4-lane group: all lanes get full sums
                #pragma unroll
                for (int bb = 0; bb < 4; ++bb)
                    #pragma unroll
                    for (int g = 0; g < 4; ++g) {
                        acc[bb][g] += __shfl_xor(acc[bb][g], 1);
                        acc[bb][g] += __shfl_xor(acc[bb][g], 2);
                    }
                // pointwise: lane sub handles batch b0i + sub (static-index selects)
                float gv[4];
                #pragma unroll
                for (int g = 0; g < 4; ++g) {
                    const float v01 = (sub & 1) ? acc[1][g] : acc[0][g];
                    const float v23 = (sub & 1) ? acc[3][g] : acc[2][g];
                    gv[g] = bias4[g] + ((sub & 2) ? v23 : v01);
                }
                const float ig = fsig(gv[0]);
                const float fg = fsig(gv[1]);
                const float gg = ftanh(gv[2]);
                const float og = fsig(gv[3]);
                const float c  = fg * cst[0] + ig * gg;
                cst[0] = c;
                h2buf[prv][b0i + sub][u] = og * ftanh(c);
            }
        } else {
            // ---- x prefetch: x(i+1) -> xbuf[(i+1)&1] ----
            if (i + 1 < TT) {
                const size_t toff = (size_t)(i + 1) * NI;
                const float v0 = x[xg0 + toff];
                const float v1 = x[xg1 + toff];
                const float v2 = x[xg2 + toff];
                float* xb = &xbuf[prv][0][0];
                xb[xo0] = v0; xb[xo1] = v1; xb[xo2] = v2;
            }
        }
        __syncthreads();
    }

    // epilogue: out = h2(TT-1) @ Wc.T + bc ; final h2 lives in h2buf[1]
    if (tid < NB * NCLS) {
        const int b = tid >> 3, c = tid & 7;
        float acc = bc[c];
        #pragma unroll
        for (int k = 0; k < NH; ++k) acc += Wc[c * NH + k] * h2buf[1][b][k];
        out[(size_t)(bbase + b) * NCLS + c] = acc;
    }
}

extern "C" void kernel_launch(void* const* d_in, const int* in_sizes, int n_in,
                              void* d_out, int out_size, void* d_ws, size_t ws_size,
                              hipStream_t stream) {
    const float* x    = (const float*)d_in[0];
    const float* Wih0 = (const float*)d_in[1];
    const float* Whh0 = (const float*)d_in[2];
    const float* b0   = (const float*)d_in[3];
    const float* Wih1 = (const float*)d_in[4];
    const float* Whh1 = (const float*)d_in[5];
    const float* b1   = (const float*)d_in[6];
    const float* Wc   = (const float*)d_in[7];
    const float* bc   = (const float*)d_in[8];
    float* out = (float*)d_out;

    dim3 grid(BATCH / NB);
    dim3 block(BLK);
    hipLaunchKernelGGL(lstm2_kernel, grid, block, 0, stream,
                       x, Wih0, Whh0, b0, Wih1, Whh1, b1, Wc, bc, out);
}

// Round 2
// 2302.798 us; speedup vs baseline: 1.1557x; 1.0622x over previous
//
#include <hip/hip_runtime.h>

#define TT    1024   // timesteps
#define BATCH 2048
#define NI    6      // input dim
#define NH    38     // hidden
#define NCLS  8      // classes
#define NB    8      // batches per block
#define HP    40     // padded hidden row (16B-aligned; cols 38,39 stay 0)
#define BLK   512

typedef float4 F4;

__device__ __forceinline__ float fsig(float v) {
    return __fdividef(1.0f, 1.0f + __expf(-v));
}
__device__ __forceinline__ float ftanh(float v) {
    return 1.0f - __fdividef(2.0f, 1.0f + __expf(2.0f * v));
}

// guarded float4 row load: elements past `lim` read as 0 (no OOB access)
__device__ __forceinline__ F4 ldw4(const float* row, int c, int lim) {
    F4 v;
    v.x = (c + 0 < lim) ? row[c + 0] : 0.0f;
    v.y = (c + 1 < lim) ? row[c + 1] : 0.0f;
    v.z = (c + 2 < lim) ? row[c + 2] : 0.0f;
    v.w = (c + 3 < lim) ? row[c + 3] : 0.0f;
    return v;
}

// ---- macro-unrolled register kernel: NO per-thread arrays anywhere ----
// weights: 4 gates x 5 float4 (20 cols, zero-padded), named g{G}v{K}
// accumulators: a{bb}{g}, 16 named scalars

#define DOT(A, G) \
    A += G##v0.x * hA.x; A += G##v0.y * hA.y; A += G##v0.z * hA.z; A += G##v0.w * hA.w; \
    A += G##v1.x * hB.x; A += G##v1.y * hB.y; A += G##v1.z * hB.z; A += G##v1.w * hB.w; \
    A += G##v2.x * hC.x; A += G##v2.y * hC.y; A += G##v2.z * hC.z; A += G##v2.w * hC.w; \
    A += G##v3.x * hD.x; A += G##v3.y * hD.y; A += G##v3.z * hD.z; A += G##v3.w * hD.w; \
    A += G##v4.x * hE.x; A += G##v4.y * hE.y; A += G##v4.z * hE.z; A += G##v4.w * hE.w;

#define L1BATCH(bb) { \
    const float* hr = &h1buf[prv][b0i + bb][cb]; \
    const F4 hA = *(const F4*)(hr + 0),  hB = *(const F4*)(hr + 4), \
             hC = *(const F4*)(hr + 8),  hD = *(const F4*)(hr + 12), \
             hE = *(const F4*)(hr + 16); \
    const float xv0 = xbuf[cur][b0i + bb][x0 + 0]; \
    const float xv1 = xbuf[cur][b0i + bb][x0 + 1]; \
    const float xv2 = xbuf[cur][b0i + bb][x0 + 2]; \
    a##bb##0 += wx00 * xv0; a##bb##0 += wx01 * xv1; a##bb##0 += wx02 * xv2; \
    a##bb##1 += wx10 * xv0; a##bb##1 += wx11 * xv1; a##bb##1 += wx12 * xv2; \
    a##bb##2 += wx20 * xv0; a##bb##2 += wx21 * xv1; a##bb##2 += wx22 * xv2; \
    a##bb##3 += wx30 * xv0; a##bb##3 += wx31 * xv1; a##bb##3 += wx32 * xv2; \
    DOT(a##bb##0, g0) DOT(a##bb##1, g1) DOT(a##bb##2, g2) DOT(a##bb##3, g3) \
}

#define L2BATCH(bb) { \
    const float* hr = hsrc + (b0i + bb) * HP + cb; \
    const F4 hA = *(const F4*)(hr + 0),  hB = *(const F4*)(hr + 4), \
             hC = *(const F4*)(hr + 8),  hD = *(const F4*)(hr + 12), \
             hE = *(const F4*)(hr + 16); \
    DOT(a##bb##0, g0) DOT(a##bb##1, g1) DOT(a##bb##2, g2) DOT(a##bb##3, g3) \
}

#define BFLY(mask) \
    a00 += __shfl_xor(a00, mask); a01 += __shfl_xor(a01, mask); \
    a02 += __shfl_xor(a02, mask); a03 += __shfl_xor(a03, mask); \
    a10 += __shfl_xor(a10, mask); a11 += __shfl_xor(a11, mask); \
    a12 += __shfl_xor(a12, mask); a13 += __shfl_xor(a13, mask); \
    a20 += __shfl_xor(a20, mask); a21 += __shfl_xor(a21, mask); \
    a22 += __shfl_xor(a22, mask); a23 += __shfl_xor(a23, mask); \
    a30 += __shfl_xor(a30, mask); a31 += __shfl_xor(a31, mask); \
    a32 += __shfl_xor(a32, mask); a33 += __shfl_xor(a33, mask);

#define LOADROW(G, rowptr) \
    G##v0 = ldw4(rowptr, cb + 0,  NH); \
    G##v1 = ldw4(rowptr, cb + 4,  NH); \
    G##v2 = ldw4(rowptr, cb + 8,  NH); \
    G##v3 = ldw4(rowptr, cb + 12, NH); \
    G##v4 = ldw4(rowptr, cb + 16, NH);

// Role layout (8 waves, 512 threads), skewed pipeline, ONE barrier/iteration:
//   tid   0..151 : L1. pair k=tid>>1 -> (u=k%38, b0i=(k/38)*4), sub=tid&1, cb=20*sub.
//                  4 gate-rows x 20 Whh0 cols (+3 Wih0 cols), 4 batches; shfl_xor(1);
//                  pointwise 2 batches/lane.
//   tid 152..175 : x-prefetch, 2 elements each (issue-early / write-late).
//   tid 176..191 : idle.
//   tid 192..495 : L2. quad m=tid-192, k=m>>2 -> (u,b0i), sub=m&3.
//                  cols = [Wih1 | Whh1] quartered; shfl_xor(1),(2); 1 batch/lane.
//   tid 496..511 : idle (wave 7 is pure L2 otherwise).
// Iter i: L1 computes h1(i) (needs h1(i-1), x(i)); L2 computes h2(i-1)
// (needs h1(i-1), h2(i-2)). Loop i=0..TT. Final h2(TT-1) lands in h2buf[1].

__global__ __launch_bounds__(BLK, 2) void lstm2_kernel(
    const float* __restrict__ x,
    const float* __restrict__ Wih0, const float* __restrict__ Whh0, const float* __restrict__ b0,
    const float* __restrict__ Wih1, const float* __restrict__ Whh1, const float* __restrict__ b1,
    const float* __restrict__ Wc,   const float* __restrict__ bc,
    float* __restrict__ out)
{
    __shared__ __align__(16) float h1buf[2][NB][HP];
    __shared__ __align__(16) float h2buf[2][NB][HP];
    __shared__ __align__(16) float xbuf[2][NB][NI];

    const int tid   = threadIdx.x;
    const int bbase = blockIdx.x * NB;

    for (int idx = tid; idx < 2 * NB * HP; idx += BLK) {
        (&h1buf[0][0][0])[idx] = 0.0f;
        (&h2buf[0][0][0])[idx] = 0.0f;
    }
    if (tid < NB * NI) {
        const int b = tid / NI, j = tid % NI;
        xbuf[0][b][j] = x[((size_t)(bbase + b) * TT + 0) * NI + j];
    }

    const bool isL1 = (tid < 152);
    const bool isPF = (tid >= 152) && (tid < 176);
    const bool isL2 = (tid >= 192) && (tid < 496);

    int u = 0, b0i = 0, sub = 0, cb = 0, x0 = 0;
    if (isL1) {
        const int k = tid >> 1;
        u = k % NH; b0i = (k / NH) * 4; sub = tid & 1; cb = sub * 20; x0 = sub * 3;
    } else if (isL2) {
        const int m = tid - 192, k = m >> 2;
        u = k % NH; b0i = (k / NH) * 4; sub = m & 3; cb = (sub & 1) * 20;
    }

    // ---- named weight registers (no arrays -> guaranteed VGPR-resident) ----
    F4 g0v0, g0v1, g0v2, g0v3, g0v4;
    F4 g1v0, g1v1, g1v2, g1v3, g1v4;
    F4 g2v0, g2v1, g2v2, g2v3, g2v4;
    F4 g3v0, g3v1, g3v2, g3v3, g3v4;
    {
        const F4 z = {0.f, 0.f, 0.f, 0.f};
        g0v0=z; g0v1=z; g0v2=z; g0v3=z; g0v4=z;
        g1v0=z; g1v1=z; g1v2=z; g1v3=z; g1v4=z;
        g2v0=z; g2v1=z; g2v2=z; g2v3=z; g2v4=z;
        g3v0=z; g3v1=z; g3v2=z; g3v3=z; g3v4=z;
    }
    float wx00=0.f, wx01=0.f, wx02=0.f, wx10=0.f, wx11=0.f, wx12=0.f;
    float wx20=0.f, wx21=0.f, wx22=0.f, wx30=0.f, wx31=0.f, wx32=0.f;
    float bs0=0.f, bs1=0.f, bs2=0.f, bs3=0.f;

    if (isL1) {
        { const float* r = Whh0 + (size_t)(u + 0 * NH) * NH; LOADROW(g0, r) }
        { const float* r = Whh0 + (size_t)(u + 1 * NH) * NH; LOADROW(g1, r) }
        { const float* r = Whh0 + (size_t)(u + 2 * NH) * NH; LOADROW(g2, r) }
        { const float* r = Whh0 + (size_t)(u + 3 * NH) * NH; LOADROW(g3, r) }
        wx00 = Wih0[(size_t)(u + 0 * NH) * NI + x0 + 0];
        wx01 = Wih0[(size_t)(u + 0 * NH) * NI + x0 + 1];
        wx02 = Wih0[(size_t)(u + 0 * NH) * NI + x0 + 2];
        wx10 = Wih0[(size_t)(u + 1 * NH) * NI + x0 + 0];
        wx11 = Wih0[(size_t)(u + 1 * NH) * NI + x0 + 1];
        wx12 = Wih0[(size_t)(u + 1 * NH) * NI + x0 + 2];
        wx20 = Wih0[(size_t)(u + 2 * NH) * NI + x0 + 0];
        wx21 = Wih0[(size_t)(u + 2 * NH) * NI + x0 + 1];
        wx22 = Wih0[(size_t)(u + 2 * NH) * NI + x0 + 2];
        wx30 = Wih0[(size_t)(u + 3 * NH) * NI + x0 + 0];
        wx31 = Wih0[(size_t)(u + 3 * NH) * NI + x0 + 1];
        wx32 = Wih0[(size_t)(u + 3 * NH) * NI + x0 + 2];
        bs0 = b0[u]; bs1 = b0[u + NH]; bs2 = b0[u + 2 * NH]; bs3 = b0[u + 3 * NH];
    } else if (isL2) {
        const float* Wm = (sub < 2) ? Wih1 : Whh1;
        { const float* r = Wm + (size_t)(u + 0 * NH) * NH; LOADROW(g0, r) }
        { const float* r = Wm + (size_t)(u + 1 * NH) * NH; LOADROW(g1, r) }
        { const float* r = Wm + (size_t)(u + 2 * NH) * NH; LOADROW(g2, r) }
        { const float* r = Wm + (size_t)(u + 3 * NH) * NH; LOADROW(g3, r) }
        bs0 = b1[u]; bs1 = b1[u + NH]; bs2 = b1[u + 2 * NH]; bs3 = b1[u + 3 * NH];
    }

    // prefetch lanes: two x elements each
    size_t xg0 = 0, xg1 = 0;
    int    xo0 = 0, xo1 = 0;
    if (isPF) {
        const int e0 = (tid - 152) * 2, e1 = e0 + 1;
        xo0 = e0; xo1 = e1;
        xg0 = (size_t)(bbase + e0 / NI) * TT * NI + (e0 % NI);
        xg1 = (size_t)(bbase + e1 / NI) * TT * NI + (e1 % NI);
    }

    float cl0 = 0.0f, cl1 = 0.0f;   // cell states (L1: 2 batches; L2: cl0 only)

    __syncthreads();

    #pragma unroll 1
    for (int i = 0; i <= TT; ++i) {
        const int cur = i & 1, prv = cur ^ 1;

        // prefetch issue (early): x(i+1)
        float pf0 = 0.f, pf1 = 0.f;
        const bool pfGo = isPF && (i + 1 < TT);
        if (pfGo) {
            const size_t toff = (size_t)(i + 1) * NI;
            pf0 = x[xg0 + toff];
            pf1 = x[xg1 + toff];
        }

        if (isL1) {
            if (i < TT) {
                float a00=0.f,a01=0.f,a02=0.f,a03=0.f, a10=0.f,a11=0.f,a12=0.f,a13=0.f;
                float a20=0.f,a21=0.f,a22=0.f,a23=0.f, a30=0.f,a31=0.f,a32=0.f,a33=0.f;
                L1BATCH(0) L1BATCH(1) L1BATCH(2) L1BATCH(3)
                BFLY(1)
                // lane `sub` handles batches b0i + 2*sub + {0,1}
                {
                    const float pv0 = bs0 + (sub ? a20 : a00);
                    const float pv1 = bs1 + (sub ? a21 : a01);
                    const float pv2 = bs2 + (sub ? a22 : a02);
                    const float pv3 = bs3 + (sub ? a23 : a03);
                    const float ig = fsig(pv0), fg = fsig(pv1);
                    const float gg = ftanh(pv2), og = fsig(pv3);
                    const float c = fg * cl0 + ig * gg; cl0 = c;
                    h1buf[cur][b0i + 2 * sub + 0][u] = og * ftanh(c);
                }
                {
                    const float pv0 = bs0 + (sub ? a30 : a10);
                    const float pv1 = bs1 + (sub ? a31 : a11);
                    const float pv2 = bs2 + (sub ? a32 : a12);
                    const float pv3 = bs3 + (sub ? a33 : a13);
                    const float ig = fsig(pv0), fg = fsig(pv1);
                    const float gg = ftanh(pv2), og = fsig(pv3);
                    const float c = fg * cl1 + ig * gg; cl1 = c;
                    h1buf[cur][b0i + 2 * sub + 1][u] = og * ftanh(c);
                }
            }
        } else if (isL2) {
            if (i >= 1) {
                const float* hsrc = (sub < 2) ? &h1buf[prv][0][0] : &h2buf[cur][0][0];
                float a00=0.f,a01=0.f,a02=0.f,a03=0.f, a10=0.f,a11=0.f,a12=0.f,a13=0.f;
                float a20=0.f,a21=0.f,a22=0.f,a23=0.f, a30=0.f,a31=0.f,a32=0.f,a33=0.f;
                L2BATCH(0) L2BATCH(1) L2BATCH(2) L2BATCH(3)
                BFLY(1) BFLY(2)
                // lane `sub` handles batch b0i + sub
                const float t0 = (sub & 1) ? a10 : a00, s0 = (sub & 1) ? a30 : a20;
                const float t1 = (sub & 1) ? a11 : a01, s1 = (sub & 1) ? a31 : a21;
                const float t2 = (sub & 1) ? a12 : a02, s2 = (sub & 1) ? a32 : a22;
                const float t3 = (sub & 1) ? a13 : a03, s3 = (sub & 1) ? a33 : a23;
                const float pv0 = bs0 + ((sub & 2) ? s0 : t0);
                const float pv1 = bs1 + ((sub & 2) ? s1 : t1);
                const float pv2 = bs2 + ((sub & 2) ? s2 : t2);
                const float pv3 = bs3 + ((sub & 2) ? s3 : t3);
                const float ig = fsig(pv0), fg = fsig(pv1);
                const float gg = ftanh(pv2), og = fsig(pv3);
                const float c = fg * cl0 + ig * gg; cl0 = c;
                h2buf[prv][b0i + sub][u] = og * ftanh(c);
            }
        }

        // prefetch write (late): vmcnt wait lands here, hidden under compute above
        if (pfGo) {
            float* xb = &xbuf[prv][0][0];
            xb[xo0] = pf0;
            xb[xo1] = pf1;
        }
        __syncthreads();
    }

    // epilogue: out = h2(TT-1) @ Wc.T + bc ; final h2 is in h2buf[1]
    if (tid < NB * NCLS) {
        const int b = tid >> 3, c = tid & 7;
        float acc = bc[c];
        #pragma unroll
        for (int k = 0; k < NH; ++k) acc += Wc[c * NH + k] * h2buf[1][b][k];
        out[(size_t)(bbase + b) * NCLS + c] = acc;
    }
}

extern "C" void kernel_launch(void* const* d_in, const int* in_sizes, int n_in,
                              void* d_out, int out_size, void* d_ws, size_t ws_size,
                              hipStream_t stream) {
    const float* x    = (const float*)d_in[0];
    const float* Wih0 = (const float*)d_in[1];
    const float* Whh0 = (const float*)d_in[2];
    const float* b0   = (const float*)d_in[3];
    const float* Wih1 = (const float*)d_in[4];
    const float* Whh1 = (const float*)d_in[5];
    const float* b1   = (const float*)d_in[6];
    const float* Wc   = (const float*)d_in[7];
    const float* bc   = (const float*)d_in[8];
    float* out = (float*)d_out;

    dim3 grid(BATCH / NB);
    dim3 block(BLK);
    hipLaunchKernelGGL(lstm2_kernel, grid, block, 0, stream,
                       x, Wih0, Whh0, b0, Wih1, Whh1, b1, Wc, bc, out);
}